// Round 9
// baseline (213.653 us; speedup 1.0000x reference)
//
#include <hip/hip_runtime.h>

#define N_NODES 59392
#define N_EDGES 1187840
#define F_IN 116
#define F_HID 64
#define BATCH 512
#define NPG 116              // nodes per graph
#define CCAP 64              // bucket: 64 u16 = one 128B line/node; P(indeg>64)~1e-15, guarded
#define NSLS 160             // src-hist slices
#define EPSS (N_EDGES / NSLS)  // 7424 edges per src-slice (exact)
#define NBIN4 (N_NODES / 4)  // 14848 packed-u8 LDS words = 59392 B
#define NR 256               // dst ranges (radix partition)
#define RNODES (N_NODES / NR)  // 232 nodes per range (exact)
#define RCAP 5376            // per-range edge capacity (mean 4640, sigma 68 -> +10.8 sigma)
#define PART_BLK 256
#define EPP (N_EDGES / PART_BLK)  // 4640 edges per partition block (exact)
#define GPB 4                // readout blocks per graph
#define NPB (NPG / GPB)      // 29 nodes per readout block (exact)
#define SCAN_BLK (N_NODES / 256)   // 232
#define GEMM_BLK 640

typedef __attribute__((ext_vector_type(8))) short short8;
typedef __attribute__((ext_vector_type(4))) float float4v;
typedef __attribute__((ext_vector_type(2))) float float2v;
typedef __attribute__((ext_vector_type(4))) unsigned uint4v;

__device__ __forceinline__ float u2f(unsigned u) {
    union { unsigned u; float f; } x; x.u = u; return x.f;
}
__device__ __forceinline__ float bf2f(unsigned short h) {
    union { unsigned u; float f; } x; x.u = (unsigned)h << 16; return x.f;
}
__device__ __forceinline__ unsigned short f2bf(float f) {
    union { float f; unsigned u; } x; x.f = f;
    unsigned r = x.u + 0x7FFF + ((x.u >> 16) & 1);   // RNE
    return (unsigned short)(r >> 16);
}

// ---------------------------------------------------------------- 1) src histogram: FULL node range, u8-packed bins (59KB LDS)
__global__ __launch_bounds__(1024) void hist_src_kernel(const int* __restrict__ src,
                                                        unsigned char* __restrict__ cnt2s) {
    __shared__ unsigned bins[NBIN4];   // 59392 B
    int tid = threadIdx.x, slice = blockIdx.x;
    long ebase = (long)slice * EPSS;
    for (int k = tid; k < NBIN4; k += 1024) bins[k] = 0;
    __syncthreads();
    for (int k = tid; k < EPSS; k += 1024) {
        int v = src[ebase + k];
        atomicAdd(&bins[v >> 2], 1u << ((v & 3) * 8));
    }
    __syncthreads();
    unsigned* op = (unsigned*)(cnt2s + (size_t)slice * N_NODES);
    for (int k = tid; k < NBIN4; k += 1024) op[k] = bins[k];
}

// ---------------------------------------------------------------- 2) scan: out-degree sum -> onorm; zero gcur + A1h sentinel
__global__ __launch_bounds__(256) void scan_onorm_kernel(const unsigned char* __restrict__ cnt2s,
                                                         float* __restrict__ onorm,
                                                         unsigned* __restrict__ gcur,
                                                         unsigned short* __restrict__ A1h) {
    int d = blockIdx.x * 256 + threadIdx.x;
    int o = 0;
    #pragma unroll 1
    for (int i = 0; i < NSLS; i += 8) {
        int c[8];
        #pragma unroll
        for (int j = 0; j < 8; ++j) c[j] = cnt2s[(size_t)(i + j) * N_NODES + d];
        #pragma unroll
        for (int j = 0; j < 8; ++j) o += c[j];
    }
    onorm[d] = rsqrtf(fmaxf((float)o, 1.0f));
    if (blockIdx.x == 0) {
        if (threadIdx.x < NR) gcur[threadIdx.x] = 0u;
        if (threadIdx.x < 16)   // zero A1h sentinel row (poison-safe)
            ((unsigned long long*)(A1h + (size_t)N_NODES * F_HID))[threadIdx.x] = 0ull;
    }
}

// ---------------------------------------------------------------- 3) partition: radix-bucket edges by dst range
// Per-block: LDS count per range -> one reservation atomic per range -> dense
// writes into per-range segments (packed local16|src16). Replaces the old
// place scatter (41MB HBM writes for 7.6MB ebuf — R5 counters).
__global__ __launch_bounds__(256) void partition_kernel(const int* __restrict__ src,
                                                        const int* __restrict__ dst,
                                                        unsigned* __restrict__ gcur,
                                                        unsigned* __restrict__ part) {
    __shared__ unsigned cnt[NR];
    __shared__ unsigned base[NR];
    int tid = threadIdx.x;
    long ebase = (long)blockIdx.x * EPP;
    cnt[tid] = 0u;                      // blockDim == NR == 256
    __syncthreads();
    #pragma unroll 1
    for (int k = tid; k < EPP; k += 256) {
        int d = dst[ebase + k];
        atomicAdd(&cnt[d / RNODES], 1u);
    }
    __syncthreads();
    unsigned c = cnt[tid];
    base[tid] = c ? atomicAdd(&gcur[tid], c) : 0u;
    __syncthreads();
    cnt[tid] = base[tid];               // reuse as running cursor
    __syncthreads();
    #pragma unroll 1
    for (int k = tid; k < EPP; k += 256) {
        int d = dst[ebase + k];
        int s = src[ebase + k];
        int r = d / RNODES;
        int local = d - r * RNODES;
        unsigned pos = atomicAdd(&cnt[r], 1u);
        if (pos < RCAP) part[(size_t)r * RCAP + pos] = ((unsigned)local << 16) | (unsigned)s;
    }
}

// ---------------------------------------------------------------- 4) FUSED: build (blocks 0..255) | gemm1 MFMA (blocks 256..895)
// build: assemble 232 complete bucket rows in LDS, write back full dwordx4
// lines — ebuf writes exactly 7.6MB, zero amplification. True in-degree from
// cursors -> ncnt u8 (inorm computed inline downstream; no dst-hist, no scan
// offsets). LDS 30.6KB does NOT tax gemm: VGPR(148) caps at 3 blocks/CU < 5.
// gemm1: A1 = (onorm ⊙ feat) @ W1, fp32-exact hi/lo bf16 split.
__global__ __launch_bounds__(256) void build_gemm_kernel(const unsigned* __restrict__ part,
                                                         const unsigned* __restrict__ gcur,
                                                         unsigned short* __restrict__ ebuf,
                                                         unsigned char* __restrict__ ncnt,
                                                         const float* __restrict__ feat,
                                                         const float* __restrict__ W1,
                                                         const float* __restrict__ onorm,
                                                         unsigned short* __restrict__ A1h) {
    __shared__ unsigned short rows[RNODES][CCAP];   // 29696 B
    __shared__ unsigned cur[RNODES];                // 928 B
    if (blockIdx.x < NR) {
        // ---- build role
        int tid = threadIdx.x;
        int r = blockIdx.x;
        if (tid < RNODES) cur[tid] = 0u;
        __syncthreads();
        int ne = (int)gcur[r];
        if (ne > RCAP) ne = RCAP;
        const unsigned* pp = part + (size_t)r * RCAP;
        #pragma unroll 1
        for (int k = tid; k < ne; k += 256) {
            unsigned e = pp[k];
            int local = e >> 16;
            unsigned pos = atomicAdd(&cur[local], 1u);
            if (pos < CCAP) rows[local][pos] = (unsigned short)(e & 0xFFFFu);
        }
        __syncthreads();
        uint4v* eb = (uint4v*)(ebuf + (size_t)r * RNODES * CCAP);
        const uint4v* rw = (const uint4v*)rows;
        #pragma unroll 1
        for (int i = tid; i < RNODES * CCAP / 8; i += 256) eb[i] = rw[i];   // 1856 x 16B
        if (tid < RNODES) {
            unsigned n = cur[tid];
            ncnt[r * RNODES + tid] = (unsigned char)(n < 255u ? n : 255u);
        }
        return;
    }
    // ---- gemm1 role
    int lane = threadIdx.x & 63;
    int c16 = lane & 15, quad = lane >> 4;
    short8 Bhi[4][4], Blo[4][4];
    #pragma unroll
    for (int kiter = 0; kiter < 4; ++kiter) {
        #pragma unroll
        for (int t = 0; t < 4; ++t) {
            #pragma unroll
            for (int j = 0; j < 8; ++j) {
                int k = kiter * 32 + quad * 8 + j;
                float w = (k < F_IN) ? W1[k * F_HID + t * 16 + c16] : 0.f;
                unsigned short hi = f2bf(w);
                unsigned short lo = f2bf(w - bf2f(hi));
                Bhi[kiter][t][j] = (short)hi;
                Blo[kiter][t][j] = (short)lo;
            }
        }
    }
    int bid = blockIdx.x - NR;
    int wid = (bid * 256 + threadIdx.x) >> 6;
    int nwaves = (GEMM_BLK * 256) >> 6;
    const int ntiles = N_NODES / 16;   // 3712
    for (int tile = wid; tile < ntiles; tile += nwaves) {
        int base = tile * 16;
        int row = base + c16;
        float on = onorm[row];
        const float* fp = feat + (size_t)row * F_IN;
        float4v acc[4] = {{0.f,0.f,0.f,0.f},{0.f,0.f,0.f,0.f},{0.f,0.f,0.f,0.f},{0.f,0.f,0.f,0.f}};
        #pragma unroll
        for (int kiter = 0; kiter < 4; ++kiter) {
            int koff = kiter * 32 + quad * 8;
            float f[8];
            if (koff + 8 <= F_IN) {
                float4 x = *(const float4*)(fp + koff);
                float4 y = *(const float4*)(fp + koff + 4);
                f[0]=x.x; f[1]=x.y; f[2]=x.z; f[3]=x.w;
                f[4]=y.x; f[5]=y.y; f[6]=y.z; f[7]=y.w;
            } else {
                #pragma unroll
                for (int j = 0; j < 8; ++j) f[j] = (koff + j < F_IN) ? fp[koff + j] : 0.f;
            }
            short8 ah, al;
            #pragma unroll
            for (int j = 0; j < 8; ++j) {
                float v = f[j] * on;
                unsigned short hi = f2bf(v);
                ah[j] = (short)hi;
                al[j] = (short)f2bf(v - bf2f(hi));
            }
            #pragma unroll
            for (int t = 0; t < 4; ++t) {
                acc[t] = __builtin_amdgcn_mfma_f32_16x16x32_bf16(ah, Bhi[kiter][t], acc[t], 0, 0, 0);
                acc[t] = __builtin_amdgcn_mfma_f32_16x16x32_bf16(al, Bhi[kiter][t], acc[t], 0, 0, 0);
                acc[t] = __builtin_amdgcn_mfma_f32_16x16x32_bf16(ah, Blo[kiter][t], acc[t], 0, 0, 0);
            }
        }
        #pragma unroll
        for (int t = 0; t < 4; ++t) {
            #pragma unroll
            for (int r2 = 0; r2 < 4; ++r2) {
                int node = base + quad * 4 + r2;
                A1h[(size_t)node * F_HID + t * 16 + c16] = f2bf(acc[t][r2]);
            }
        }
    }
}

// ---------------------------------------------------------------- gather core: TWO nodes per wave, 16 independent 128B row loads
// Full-row layout (row = one cache line). Index/bucket loads NONTEMPORAL.
// Invalid slots -> row N_NODES (zeroed sentinel row -> contributes 0).
// UNCONDITIONAL 8-group issue (R8 lesson: guarding groups breaks load batching
// and serializes latency — sentinel loads are nearly free, all hit one line).
// Channel pairs accumulated as float2 -> v_pk_add_f32.
__device__ __forceinline__ void gather2n(const unsigned* __restrict__ base,
                                         const unsigned short* __restrict__ ebuf,
                                         int va, int vb, int na, int nb,
                                         int c16, int g4, int sh16,
                                         float& a0, float& a1, float& a2, float& a3,
                                         float& b0, float& b1, float& b2, float& b3) {
    const unsigned long long* ea = (const unsigned long long*)(ebuf + (size_t)va * CCAP);
    const unsigned long long* eb = (const unsigned long long*)(ebuf + (size_t)vb * CCAP);
    unsigned long long cha[8], chb[8];
    #pragma unroll
    for (int t = 0; t < 8; ++t) cha[t] = __builtin_nontemporal_load(&ea[t]);
    #pragma unroll
    for (int t = 0; t < 8; ++t) chb[t] = __builtin_nontemporal_load(&eb[t]);
    int ida[8], idb[8];
    #pragma unroll
    for (int t = 0; t < 8; ++t) {
        ida[t] = (t * 4 + g4 < na) ? (int)((cha[t] >> sh16) & 0xFFFFu) : N_NODES;
        idb[t] = (t * 4 + g4 < nb) ? (int)((chb[t] >> sh16) & 0xFFFFu) : N_NODES;
    }
    unsigned long long rwa[8], rwb[8];
    #pragma unroll
    for (int t = 0; t < 8; ++t) rwa[t] = *(const unsigned long long*)(base + ida[t] * 32 + c16 * 2);
    #pragma unroll
    for (int t = 0; t < 8; ++t) rwb[t] = *(const unsigned long long*)(base + idb[t] * 32 + c16 * 2);
    float2v A01 = {0.f, 0.f}, A23 = {0.f, 0.f}, B01 = {0.f, 0.f}, B23 = {0.f, 0.f};
    #pragma unroll
    for (int t = 0; t < 8; ++t) {
        unsigned lo = (unsigned)rwa[t], hi = (unsigned)(rwa[t] >> 32);
        float2v x; x.x = u2f(lo << 16); x.y = u2f(lo & 0xFFFF0000u);
        float2v y; y.x = u2f(hi << 16); y.y = u2f(hi & 0xFFFF0000u);
        A01 += x; A23 += y;
    }
    #pragma unroll
    for (int t = 0; t < 8; ++t) {
        unsigned lo = (unsigned)rwb[t], hi = (unsigned)(rwb[t] >> 32);
        float2v x; x.x = u2f(lo << 16); x.y = u2f(lo & 0xFFFF0000u);
        float2v y; y.x = u2f(hi << 16); y.y = u2f(hi & 0xFFFF0000u);
        B01 += x; B23 += y;
    }
    int nqa = (na + 3) >> 2;
    #pragma unroll 1
    for (int t = 8; t < nqa; ++t) {          // rare: n > 32
        unsigned long long c = __builtin_nontemporal_load(&ea[t]);
        int e = t * 4 + g4;
        int ix = (e < na) ? (int)((c >> sh16) & 0xFFFFu) : N_NODES;
        unsigned long long w = *(const unsigned long long*)(base + ix * 32 + c16 * 2);
        unsigned lo = (unsigned)w, hi = (unsigned)(w >> 32);
        float2v x; x.x = u2f(lo << 16); x.y = u2f(lo & 0xFFFF0000u);
        float2v y; y.x = u2f(hi << 16); y.y = u2f(hi & 0xFFFF0000u);
        A01 += x; A23 += y;
    }
    int nqb = (nb + 3) >> 2;
    #pragma unroll 1
    for (int t = 8; t < nqb; ++t) {
        unsigned long long c = __builtin_nontemporal_load(&eb[t]);
        int e = t * 4 + g4;
        int ix = (e < nb) ? (int)((c >> sh16) & 0xFFFFu) : N_NODES;
        unsigned long long w = *(const unsigned long long*)(base + ix * 32 + c16 * 2);
        unsigned lo = (unsigned)w, hi = (unsigned)(w >> 32);
        float2v x; x.x = u2f(lo << 16); x.y = u2f(lo & 0xFFFF0000u);
        float2v y; y.x = u2f(hi << 16); y.y = u2f(hi & 0xFFFF0000u);
        B01 += x; B23 += y;
    }
    a0 = A01.x; a1 = A01.y; a2 = A23.x; a3 = A23.y;
    b0 = B01.x; b1 = B01.y; b2 = B23.x; b3 = B23.y;
    a0 += __shfl_xor(a0, 16); a1 += __shfl_xor(a1, 16);
    a2 += __shfl_xor(a2, 16); a3 += __shfl_xor(a3, 16);
    a0 += __shfl_xor(a0, 32); a1 += __shfl_xor(a1, 32);
    a2 += __shfl_xor(a2, 32); a3 += __shfl_xor(a3, 32);
    b0 += __shfl_xor(b0, 16); b1 += __shfl_xor(b1, 16);
    b2 += __shfl_xor(b2, 16); b3 += __shfl_xor(b3, 16);
    b0 += __shfl_xor(b0, 32); b1 += __shfl_xor(b1, 32);
    b2 += __shfl_xor(b2, 32); b3 += __shfl_xor(b3, 32);
}

// ---------------------------------------------------------------- 5) gather1: 2 nodes/wave; H1' = onorm_v ⊙ relu(inorm_v ⊙ Σ A1'[u] + b1)
__global__ __launch_bounds__(256) void gather1_kernel(const unsigned char* __restrict__ ncnt,
                                                      const unsigned short* __restrict__ ebuf,
                                                      const unsigned short* __restrict__ A1h,
                                                      const float* __restrict__ onorm,
                                                      const float* __restrict__ b1,
                                                      unsigned short* __restrict__ H1h,
                                                      float* __restrict__ out) {
    if (blockIdx.x == 0) {
        int t = threadIdx.x;
        for (int k = t; k < BATCH * 2; k += 256) out[k] = 0.f;
        if (t < 16) ((unsigned long long*)(H1h + (size_t)N_NODES * F_HID))[t] = 0ull;
    }
    int lane = threadIdx.x & 63;
    int wu = __builtin_amdgcn_readfirstlane(threadIdx.x >> 6);   // uniform wave id
    int c16 = lane & 15, g4 = lane >> 4, sh16 = g4 * 16;
    int va = blockIdx.x * 8 + wu * 2;          // grid = N_NODES/8 = 7424, exact
    int vb = va + 1;
    int da = ncnt[va], db = ncnt[vb];          // uniform u8 loads (true in-degree)
    int na = da < CCAP ? da : CCAP;
    int nb = db < CCAP ? db : CCAP;
    const unsigned* base = (const unsigned*)A1h;
    float4 b1q = ((const float4*)b1)[c16];
    float a0, a1, a2, a3, b0, b1v, b2v, b3;
    gather2n(base, ebuf, va, vb, na, nb, c16, g4, sh16,
             a0, a1, a2, a3, b0, b1v, b2v, b3);
    float ina = rsqrtf(fmaxf((float)da, 1.f));
    float inb = rsqrtf(fmaxf((float)db, 1.f));
    float ona = onorm[va], onb = onorm[vb];
    float ha0 = fmaxf(ina * a0 + b1q.x, 0.f) * ona;
    float ha1 = fmaxf(ina * a1 + b1q.y, 0.f) * ona;
    float ha2 = fmaxf(ina * a2 + b1q.z, 0.f) * ona;
    float ha3 = fmaxf(ina * a3 + b1q.w, 0.f) * ona;
    float hb0 = fmaxf(inb * b0 + b1q.x, 0.f) * onb;
    float hb1 = fmaxf(inb * b1v + b1q.y, 0.f) * onb;
    float hb2 = fmaxf(inb * b2v + b1q.z, 0.f) * onb;
    float hb3 = fmaxf(inb * b3 + b1q.w, 0.f) * onb;
    if (g4 == 0) {
        unsigned lo = (unsigned)f2bf(ha0) | ((unsigned)f2bf(ha1) << 16);
        unsigned hi = (unsigned)f2bf(ha2) | ((unsigned)f2bf(ha3) << 16);
        ((unsigned long long*)H1h)[(size_t)va * 16 + c16] = ((unsigned long long)hi << 32) | lo;
        lo = (unsigned)f2bf(hb0) | ((unsigned)f2bf(hb1) << 16);
        hi = (unsigned)f2bf(hb2) | ((unsigned)f2bf(hb3) << 16);
        ((unsigned long long*)H1h)[(size_t)vb * 16 + c16] = ((unsigned long long)hi << 32) | lo;
    }
}

// ---------------------------------------------------------------- 6) readout: 4 blocks/graph, 2-node gather pairs
__global__ __launch_bounds__(256) void readout_kernel(const unsigned char* __restrict__ ncnt,
                                                      const unsigned short* __restrict__ ebuf,
                                                      const unsigned short* __restrict__ H1h,
                                                      const float* __restrict__ b2,
                                                      const float* __restrict__ W2,
                                                      const float* __restrict__ Wc,
                                                      const float* __restrict__ bc,
                                                      float* __restrict__ out) {
    __shared__ float Gs[NPB][F_HID];   // 7424 B
    __shared__ float ls[8];
    int g = blockIdx.x >> 2, part = blockIdx.x & 3;
    int nbase = g * NPG + part * NPB;
    int lane = threadIdx.x & 63;
    int wu = __builtin_amdgcn_readfirstlane(threadIdx.x >> 6);
    int c16 = lane & 15, g4 = lane >> 4, sh16 = g4 * 16;
    const unsigned* base = (const unsigned*)H1h;
    // ---- phase 1: gather pairs (waves cover nodes 0..27; node 28 by wave 2)
    for (int nl = wu * 2; nl + 1 < NPB; nl += 8) {
        int va = nbase + nl, vb = va + 1;
        int da = ncnt[va], db = ncnt[vb];
        int na = da < CCAP ? da : CCAP;
        int nb = db < CCAP ? db : CCAP;
        float a0, a1, a2, a3, b0, b1, b2v, b3;
        gather2n(base, ebuf, va, vb, na, nb, c16, g4, sh16,
                 a0, a1, a2, a3, b0, b1, b2v, b3);
        if (g4 == 0) {
            float4 m4; m4.x = a0; m4.y = a1; m4.z = a2; m4.w = a3;
            *(float4*)&Gs[nl][c16 * 4] = m4;
            m4.x = b0; m4.y = b1; m4.z = b2v; m4.w = b3;
            *(float4*)&Gs[nl + 1][c16 * 4] = m4;
        }
    }
    if (wu == 2) {   // leftover node 28
        int v = nbase + 28;
        int dv = ncnt[v];
        int n = dv < CCAP ? dv : CCAP;
        float a0, a1, a2, a3, d0, d1, d2, d3;
        gather2n(base, ebuf, v, v, n, 0, c16, g4, sh16,
                 a0, a1, a2, a3, d0, d1, d2, d3);
        if (g4 == 0) {
            float4 m4; m4.x = a0; m4.y = a1; m4.z = a2; m4.w = a3;
            *(float4*)&Gs[28][c16 * 4] = m4;
        }
    }
    __syncthreads();
    // ---- phase 2: W2 matvec + activation + Wc dot
    float w2[F_HID];
    #pragma unroll
    for (int k = 0; k < F_HID; ++k) w2[k] = W2[k * F_HID + lane];
    float b2l = b2[lane];
    float s0 = 0.f, s1 = 0.f;
    for (int nl = wu; nl < NPB; nl += 4) {
        int v = nbase + nl;
        float acc = 0.f;
        #pragma unroll
        for (int k = 0; k < F_HID; k += 4) {
            float4 gk = *(const float4*)&Gs[nl][k];   // uniform addr: LDS broadcast
            acc += gk.x * w2[k] + gk.y * w2[k + 1] + gk.z * w2[k + 2] + gk.w * w2[k + 3];
        }
        float inv = rsqrtf(fmaxf((float)ncnt[v], 1.f));
        float h = fmaxf(inv * acc + b2l, 0.f);
        float2 w = ((const float2*)Wc)[(part * NPB + nl) * F_HID + lane];
        s0 += h * w.x;
        s1 += h * w.y;
    }
    #pragma unroll
    for (int off = 32; off > 0; off >>= 1) {
        s0 += __shfl_down(s0, off);
        s1 += __shfl_down(s1, off);
    }
    if (lane == 0) { ls[wu * 2] = s0; ls[wu * 2 + 1] = s1; }
    __syncthreads();
    if (threadIdx.x < 2) {
        float t = 0.f;
        #pragma unroll
        for (int w = 0; w < 4; ++w) t += ls[w * 2 + threadIdx.x];
        if (part == 0) t += bc[threadIdx.x];
        atomicAdd(&out[g * 2 + threadIdx.x], t);
    }
}

extern "C" void kernel_launch(void* const* d_in, const int* in_sizes, int n_in,
                              void* d_out, int out_size, void* d_ws, size_t ws_size,
                              hipStream_t stream) {
    const float* feat = (const float*)d_in[0];
    const int*   src  = (const int*)d_in[1];
    const int*   dst  = (const int*)d_in[2];
    // d_in[3] = batch_size (fixed 512)
    const float* W1 = (const float*)d_in[4];
    const float* b1 = (const float*)d_in[5];
    const float* W2 = (const float*)d_in[6];
    const float* b2 = (const float*)d_in[7];
    const float* Wc = (const float*)d_in[8];
    const float* bc = (const float*)d_in[9];
    float* out = (float*)d_out;

    // ws layout (≈30.5 MB):
    // cnt2s u8[NSLS*N] (9.5MB) | onorm f32[N+1] | gcur u32[NR] | ncnt u8[N]
    // | (256B-aligned) part u32[NR*RCAP] (5.5MB) | ebuf u16[N*CCAP] (7.6MB)
    // | A1h bf16[(N+1)*64] (7.6MB)
    // H1h (7.6MB) ALIASES cnt2s (9.5MB; dead after scan_onorm).
    unsigned char* cnt2s = (unsigned char*)d_ws;
    float* onorm = (float*)(cnt2s + (size_t)NSLS * N_NODES);
    unsigned* gcur = (unsigned*)(onorm + N_NODES + 1);
    unsigned char* ncnt = (unsigned char*)(gcur + NR);
    unsigned* part = (unsigned*)(((unsigned long long)(ncnt + N_NODES) + 255ull) & ~255ull);
    unsigned short* ebuf = (unsigned short*)(part + (size_t)NR * RCAP);
    unsigned short* A1h  = ebuf + (size_t)N_NODES * CCAP;
    unsigned short* H1h  = (unsigned short*)cnt2s;   // alias

    hist_src_kernel<<<NSLS, 1024, 0, stream>>>(src, cnt2s);
    scan_onorm_kernel<<<SCAN_BLK, 256, 0, stream>>>(cnt2s, onorm, gcur, A1h);
    partition_kernel<<<PART_BLK, 256, 0, stream>>>(src, dst, gcur, part);
    build_gemm_kernel<<<NR + GEMM_BLK, 256, 0, stream>>>(part, gcur, ebuf, ncnt,
                                                         feat, W1, onorm, A1h);
    gather1_kernel<<<N_NODES / 8, 256, 0, stream>>>(ncnt, ebuf, A1h, onorm, b1, H1h, out);
    readout_kernel<<<BATCH * GPB, 256, 0, stream>>>(ncnt, ebuf, H1h, b2, W2, Wc, bc, out);
}

// Round 10
// 189.139 us; speedup vs baseline: 1.1296x; 1.1296x over previous
//
#include <hip/hip_runtime.h>

#define N_NODES 59392
#define N_EDGES 1187840
#define F_IN 116
#define F_HID 64
#define BATCH 512
#define NPG 116              // nodes per graph
#define CCAP 64              // bucket: 64 u16 = one 128B line/node; P(indeg>64)~1e-15, guarded
#define NSLD 80              // dst-hist / place slices (balanced with src)
#define EPSD (N_EDGES / NSLD)  // 14848 edges per dst-slice (exact)
#define NSLS 80              // src-hist slices
#define EPSS (N_EDGES / NSLS)  // 14848 edges per src-slice (exact)
#define NBIN4 (N_NODES / 4)  // 14848 packed-u8 LDS words = 59392 B (2 blocks/CU)
#define GPB 4                // readout blocks per graph
#define NPB (NPG / GPB)      // 29 nodes per readout block (exact)
#define SCAN_BLK (N_NODES / 256)   // 232
#define GEMM_BLK 640

typedef __attribute__((ext_vector_type(8))) short short8;
typedef __attribute__((ext_vector_type(4))) float float4v;
typedef __attribute__((ext_vector_type(2))) float float2v;

__device__ __forceinline__ float u2f(unsigned u) {
    union { unsigned u; float f; } x; x.u = u; return x.f;
}
__device__ __forceinline__ float bf2f(unsigned short h) {
    union { unsigned u; float f; } x; x.u = (unsigned)h << 16; return x.f;
}
__device__ __forceinline__ unsigned short f2bf(float f) {
    union { float f; unsigned u; } x; x.f = f;
    unsigned r = x.u + 0x7FFF + ((x.u >> 16) & 1);   // RNE
    return (unsigned short)(r >> 16);
}

// ---------------------------------------------------------------- 1) histograms: FULL node range, u8-packed bins (59KB LDS), edges read 1x
// 80 dst + 80 src blocks, all 14848 edges each (balanced tail).
__global__ __launch_bounds__(1024) void hist_kernel(const int* __restrict__ src,
                                                    const int* __restrict__ dst,
                                                    unsigned char* __restrict__ cnt2,
                                                    unsigned char* __restrict__ cnt2s) {
    __shared__ unsigned bins[NBIN4];   // 59392 B
    int tid = threadIdx.x;
    int b = blockIdx.x;
    const int* __restrict__ idx;
    unsigned char* outp;
    int slice;
    if (b < NSLD) {
        slice = b; idx = dst; outp = cnt2;
    } else {
        slice = b - NSLD; idx = src; outp = cnt2s;
    }
    long ebase = (long)slice * EPSD;
    for (int k = tid; k < NBIN4; k += 1024) bins[k] = 0;
    __syncthreads();
    for (int k = tid; k < EPSD; k += 1024) {
        int v = idx[ebase + k];
        atomicAdd(&bins[v >> 2], 1u << ((v & 3) * 8));
    }
    __syncthreads();
    unsigned* op = (unsigned*)(outp + (size_t)slice * N_NODES);
    for (int k = tid; k < NBIN4; k += 1024) op[k] = bins[k];
}

// ---------------------------------------------------------------- 2) scan: u8 offsets (in-degree max ~47 < 255) + norms
__global__ __launch_bounds__(256) void scan_kernel(unsigned char* __restrict__ cnt2,
                                                   const unsigned char* __restrict__ cnt2s,
                                                   float* __restrict__ onorm,
                                                   float* __restrict__ inorm,
                                                   int* __restrict__ ncnt,
                                                   unsigned short* __restrict__ A1h) {
    int d = blockIdx.x * 256 + threadIdx.x;
    int run = 0;
    #pragma unroll 1
    for (int i = 0; i < NSLD; i += 8) {
        int c[8];
        #pragma unroll
        for (int j = 0; j < 8; ++j) c[j] = cnt2[(size_t)(i + j) * N_NODES + d];
        #pragma unroll
        for (int j = 0; j < 8; ++j) {
            cnt2[(size_t)(i + j) * N_NODES + d] = (unsigned char)run;
            run += c[j];
        }
    }
    int o = 0;
    #pragma unroll 1
    for (int i = 0; i < NSLS; i += 8) {
        int c[8];
        #pragma unroll
        for (int j = 0; j < 8; ++j) c[j] = cnt2s[(size_t)(i + j) * N_NODES + d];
        #pragma unroll
        for (int j = 0; j < 8; ++j) o += c[j];
    }
    onorm[d] = rsqrtf(fmaxf((float)o, 1.0f));
    inorm[d] = rsqrtf(fmaxf((float)run, 1.0f));
    ncnt[d] = run < CCAP ? run : CCAP;
    if (blockIdx.x == 0 && threadIdx.x < 16)  // zero A1h sentinel row (poison-safe)
        ((unsigned long long*)(A1h + (size_t)N_NODES * F_HID))[threadIdx.x] = 0ull;
}

// ---------------------------------------------------------------- 3) FUSED: place (blocks 0..79, u8 cursors) | gemm1 MFMA (blocks 80..719)
// gemm1 pre-scales feat rows by onorm (reference order: h = feat*out_norm, THEN @W1)
// -> gather1 needs no per-neighbor onorm loads. Single bf16 rounding, MFMA fp32-exact.
__global__ __launch_bounds__(256) void gemm_place_kernel(const int* __restrict__ src,
                                                         const int* __restrict__ dst,
                                                         const unsigned char* __restrict__ cnt2,
                                                         unsigned short* __restrict__ ebuf,
                                                         const float* __restrict__ feat,
                                                         const float* __restrict__ W1,
                                                         const float* __restrict__ onorm,
                                                         unsigned short* __restrict__ A1h) {
    __shared__ unsigned cur[NBIN4];    // 59392 B (reserved by all blocks; 2 blocks/CU)
    if (blockIdx.x < NSLD) {
        // ---- place role
        int tid = threadIdx.x;
        int slice = blockIdx.x;
        long ebase = (long)slice * EPSD;
        const unsigned* pp = (const unsigned*)(cnt2 + (size_t)slice * N_NODES);
        for (int k = tid; k < NBIN4; k += 256) cur[k] = pp[k];
        __syncthreads();
        #pragma unroll 1
        for (int t = 0; t < 14; ++t) {     // 14*1024 = 14336 edges in quads
            int k = t * 1024 + tid;
            int d0 = dst[ebase + k],        s0 = src[ebase + k];
            int d1 = dst[ebase + k + 256],  s1 = src[ebase + k + 256];
            int d2 = dst[ebase + k + 512],  s2 = src[ebase + k + 512];
            int d3 = dst[ebase + k + 768],  s3 = src[ebase + k + 768];
            #define PLACE1(dd, ss)                                                    \
                { int sh = ((dd) & 3) * 8;                                            \
                  unsigned old = atomicAdd(&cur[(dd) >> 2], 1u << sh);                \
                  unsigned pos = (old >> sh) & 0xFFu;                                 \
                  if (pos < CCAP) ebuf[(size_t)(dd) * CCAP + pos] = (unsigned short)(ss); }
            PLACE1(d0, s0) PLACE1(d1, s1) PLACE1(d2, s2) PLACE1(d3, s3)
        }
        {   // tail: edges [14336, 14848) = two 256-strips
            int k = 14336 + tid;
            int d0 = dst[ebase + k], s0 = src[ebase + k];
            PLACE1(d0, s0)
            k = 14592 + tid;
            d0 = dst[ebase + k]; s0 = src[ebase + k];
            PLACE1(d0, s0)
            #undef PLACE1
        }
        return;
    }
    // ---- gemm1 role: A1 = (onorm ⊙ feat) @ W1 (bf16 out, hi/lo split = fp32-exact)
    int lane = threadIdx.x & 63;
    int c16 = lane & 15, quad = lane >> 4;
    short8 Bhi[4][4], Blo[4][4];
    #pragma unroll
    for (int kiter = 0; kiter < 4; ++kiter) {
        #pragma unroll
        for (int t = 0; t < 4; ++t) {
            #pragma unroll
            for (int j = 0; j < 8; ++j) {
                int k = kiter * 32 + quad * 8 + j;
                float w = (k < F_IN) ? W1[k * F_HID + t * 16 + c16] : 0.f;
                unsigned short hi = f2bf(w);
                unsigned short lo = f2bf(w - bf2f(hi));
                Bhi[kiter][t][j] = (short)hi;
                Blo[kiter][t][j] = (short)lo;
            }
        }
    }
    int bid = blockIdx.x - NSLD;
    int wid = (bid * 256 + threadIdx.x) >> 6;
    int nwaves = (GEMM_BLK * 256) >> 6;
    const int ntiles = N_NODES / 16;   // 3712
    for (int tile = wid; tile < ntiles; tile += nwaves) {
        int base = tile * 16;
        int row = base + c16;
        float on = onorm[row];
        const float* fp = feat + (size_t)row * F_IN;
        float4v acc[4] = {{0.f,0.f,0.f,0.f},{0.f,0.f,0.f,0.f},{0.f,0.f,0.f,0.f},{0.f,0.f,0.f,0.f}};
        #pragma unroll
        for (int kiter = 0; kiter < 4; ++kiter) {
            int koff = kiter * 32 + quad * 8;
            float f[8];
            if (koff + 8 <= F_IN) {
                float4 x = *(const float4*)(fp + koff);
                float4 y = *(const float4*)(fp + koff + 4);
                f[0]=x.x; f[1]=x.y; f[2]=x.z; f[3]=x.w;
                f[4]=y.x; f[5]=y.y; f[6]=y.z; f[7]=y.w;
            } else {
                #pragma unroll
                for (int j = 0; j < 8; ++j) f[j] = (koff + j < F_IN) ? fp[koff + j] : 0.f;
            }
            short8 ah, al;
            #pragma unroll
            for (int j = 0; j < 8; ++j) {
                float v = f[j] * on;
                unsigned short hi = f2bf(v);
                ah[j] = (short)hi;
                al[j] = (short)f2bf(v - bf2f(hi));
            }
            #pragma unroll
            for (int t = 0; t < 4; ++t) {
                acc[t] = __builtin_amdgcn_mfma_f32_16x16x32_bf16(ah, Bhi[kiter][t], acc[t], 0, 0, 0);
                acc[t] = __builtin_amdgcn_mfma_f32_16x16x32_bf16(al, Bhi[kiter][t], acc[t], 0, 0, 0);
                acc[t] = __builtin_amdgcn_mfma_f32_16x16x32_bf16(ah, Blo[kiter][t], acc[t], 0, 0, 0);
            }
        }
        #pragma unroll
        for (int t = 0; t < 4; ++t) {
            #pragma unroll
            for (int r = 0; r < 4; ++r) {
                int node = base + quad * 4 + r;
                A1h[(size_t)node * F_HID + t * 16 + c16] = f2bf(acc[t][r]);
            }
        }
    }
}

// ---------------------------------------------------------------- gather core: TWO nodes per wave, 16 independent 128B row loads
// Full-row layout (row = one cache line). Index/bucket loads NONTEMPORAL.
// Invalid slots -> row N_NODES (zeroed sentinel row -> contributes 0).
// UNCONDITIONAL 8-group issue (R8 lesson: guarding groups breaks load batching).
// Channel pairs accumulated as float2 -> v_pk_add_f32.
__device__ __forceinline__ void gather2n(const unsigned* __restrict__ base,
                                         const unsigned short* __restrict__ ebuf,
                                         int va, int vb, int na, int nb,
                                         int c16, int g4, int sh16,
                                         float& a0, float& a1, float& a2, float& a3,
                                         float& b0, float& b1, float& b2, float& b3) {
    const unsigned long long* ea = (const unsigned long long*)(ebuf + (size_t)va * CCAP);
    const unsigned long long* eb = (const unsigned long long*)(ebuf + (size_t)vb * CCAP);
    unsigned long long cha[8], chb[8];
    #pragma unroll
    for (int t = 0; t < 8; ++t) cha[t] = __builtin_nontemporal_load(&ea[t]);
    #pragma unroll
    for (int t = 0; t < 8; ++t) chb[t] = __builtin_nontemporal_load(&eb[t]);
    int ida[8], idb[8];
    #pragma unroll
    for (int t = 0; t < 8; ++t) {
        ida[t] = (t * 4 + g4 < na) ? (int)((cha[t] >> sh16) & 0xFFFFu) : N_NODES;
        idb[t] = (t * 4 + g4 < nb) ? (int)((chb[t] >> sh16) & 0xFFFFu) : N_NODES;
    }
    unsigned long long rwa[8], rwb[8];
    #pragma unroll
    for (int t = 0; t < 8; ++t) rwa[t] = *(const unsigned long long*)(base + ida[t] * 32 + c16 * 2);
    #pragma unroll
    for (int t = 0; t < 8; ++t) rwb[t] = *(const unsigned long long*)(base + idb[t] * 32 + c16 * 2);
    float2v A01 = {0.f, 0.f}, A23 = {0.f, 0.f}, B01 = {0.f, 0.f}, B23 = {0.f, 0.f};
    #pragma unroll
    for (int t = 0; t < 8; ++t) {
        unsigned lo = (unsigned)rwa[t], hi = (unsigned)(rwa[t] >> 32);
        float2v x; x.x = u2f(lo << 16); x.y = u2f(lo & 0xFFFF0000u);
        float2v y; y.x = u2f(hi << 16); y.y = u2f(hi & 0xFFFF0000u);
        A01 += x; A23 += y;
    }
    #pragma unroll
    for (int t = 0; t < 8; ++t) {
        unsigned lo = (unsigned)rwb[t], hi = (unsigned)(rwb[t] >> 32);
        float2v x; x.x = u2f(lo << 16); x.y = u2f(lo & 0xFFFF0000u);
        float2v y; y.x = u2f(hi << 16); y.y = u2f(hi & 0xFFFF0000u);
        B01 += x; B23 += y;
    }
    int nqa = (na + 3) >> 2;
    #pragma unroll 1
    for (int t = 8; t < nqa; ++t) {          // rare: n > 32
        unsigned long long c = __builtin_nontemporal_load(&ea[t]);
        int e = t * 4 + g4;
        int ix = (e < na) ? (int)((c >> sh16) & 0xFFFFu) : N_NODES;
        unsigned long long w = *(const unsigned long long*)(base + ix * 32 + c16 * 2);
        unsigned lo = (unsigned)w, hi = (unsigned)(w >> 32);
        float2v x; x.x = u2f(lo << 16); x.y = u2f(lo & 0xFFFF0000u);
        float2v y; y.x = u2f(hi << 16); y.y = u2f(hi & 0xFFFF0000u);
        A01 += x; A23 += y;
    }
    int nqb = (nb + 3) >> 2;
    #pragma unroll 1
    for (int t = 8; t < nqb; ++t) {
        unsigned long long c = __builtin_nontemporal_load(&eb[t]);
        int e = t * 4 + g4;
        int ix = (e < nb) ? (int)((c >> sh16) & 0xFFFFu) : N_NODES;
        unsigned long long w = *(const unsigned long long*)(base + ix * 32 + c16 * 2);
        unsigned lo = (unsigned)w, hi = (unsigned)(w >> 32);
        float2v x; x.x = u2f(lo << 16); x.y = u2f(lo & 0xFFFF0000u);
        float2v y; y.x = u2f(hi << 16); y.y = u2f(hi & 0xFFFF0000u);
        B01 += x; B23 += y;
    }
    a0 = A01.x; a1 = A01.y; a2 = A23.x; a3 = A23.y;
    b0 = B01.x; b1 = B01.y; b2 = B23.x; b3 = B23.y;
    a0 += __shfl_xor(a0, 16); a1 += __shfl_xor(a1, 16);
    a2 += __shfl_xor(a2, 16); a3 += __shfl_xor(a3, 16);
    a0 += __shfl_xor(a0, 32); a1 += __shfl_xor(a1, 32);
    a2 += __shfl_xor(a2, 32); a3 += __shfl_xor(a3, 32);
    b0 += __shfl_xor(b0, 16); b1 += __shfl_xor(b1, 16);
    b2 += __shfl_xor(b2, 16); b3 += __shfl_xor(b3, 16);
    b0 += __shfl_xor(b0, 32); b1 += __shfl_xor(b1, 32);
    b2 += __shfl_xor(b2, 32); b3 += __shfl_xor(b3, 32);
}

// ---------------------------------------------------------------- 4) gather1: 2 nodes/wave; H1' = onorm_v ⊙ relu(inorm_v ⊙ Σ A1'[u] + b1)
__global__ __launch_bounds__(256) void gather1_kernel(const int* __restrict__ ncnt,
                                                      const unsigned short* __restrict__ ebuf,
                                                      const unsigned short* __restrict__ A1h,
                                                      const float* __restrict__ onorm,
                                                      const float* __restrict__ inorm,
                                                      const float* __restrict__ b1,
                                                      unsigned short* __restrict__ H1h,
                                                      float* __restrict__ out) {
    if (blockIdx.x == 0) {
        int t = threadIdx.x;
        for (int k = t; k < BATCH * 2; k += 256) out[k] = 0.f;
        if (t < 16) ((unsigned long long*)(H1h + (size_t)N_NODES * F_HID))[t] = 0ull;
    }
    int lane = threadIdx.x & 63;
    int wu = __builtin_amdgcn_readfirstlane(threadIdx.x >> 6);   // uniform wave id
    int c16 = lane & 15, g4 = lane >> 4, sh16 = g4 * 16;
    int va = blockIdx.x * 8 + wu * 2;          // grid = N_NODES/8 = 7424, exact
    int vb = va + 1;
    int na = ncnt[va], nb = ncnt[vb];          // uniform -> scalar loads
    const unsigned* base = (const unsigned*)A1h;
    float4 b1q = ((const float4*)b1)[c16];
    float a0, a1, a2, a3, b0, b1v, b2v, b3;
    gather2n(base, ebuf, va, vb, na, nb, c16, g4, sh16,
             a0, a1, a2, a3, b0, b1v, b2v, b3);
    float ina = inorm[va], ona = onorm[va];
    float inb = inorm[vb], onb = onorm[vb];
    float ha0 = fmaxf(ina * a0 + b1q.x, 0.f) * ona;
    float ha1 = fmaxf(ina * a1 + b1q.y, 0.f) * ona;
    float ha2 = fmaxf(ina * a2 + b1q.z, 0.f) * ona;
    float ha3 = fmaxf(ina * a3 + b1q.w, 0.f) * ona;
    float hb0 = fmaxf(inb * b0 + b1q.x, 0.f) * onb;
    float hb1 = fmaxf(inb * b1v + b1q.y, 0.f) * onb;
    float hb2 = fmaxf(inb * b2v + b1q.z, 0.f) * onb;
    float hb3 = fmaxf(inb * b3 + b1q.w, 0.f) * onb;
    if (g4 == 0) {
        unsigned lo = (unsigned)f2bf(ha0) | ((unsigned)f2bf(ha1) << 16);
        unsigned hi = (unsigned)f2bf(ha2) | ((unsigned)f2bf(ha3) << 16);
        ((unsigned long long*)H1h)[(size_t)va * 16 + c16] = ((unsigned long long)hi << 32) | lo;
        lo = (unsigned)f2bf(hb0) | ((unsigned)f2bf(hb1) << 16);
        hi = (unsigned)f2bf(hb2) | ((unsigned)f2bf(hb3) << 16);
        ((unsigned long long*)H1h)[(size_t)vb * 16 + c16] = ((unsigned long long)hi << 32) | lo;
    }
}

// ---------------------------------------------------------------- 5) readout: 4 blocks/graph, 2-node gather pairs
__global__ __launch_bounds__(256) void readout_kernel(const int* __restrict__ ncnt,
                                                      const unsigned short* __restrict__ ebuf,
                                                      const unsigned short* __restrict__ H1h,
                                                      const float* __restrict__ inorm,
                                                      const float* __restrict__ b2,
                                                      const float* __restrict__ W2,
                                                      const float* __restrict__ Wc,
                                                      const float* __restrict__ bc,
                                                      float* __restrict__ out) {
    __shared__ float Gs[NPB][F_HID];   // 7424 B
    __shared__ float ls[8];
    int g = blockIdx.x >> 2, part = blockIdx.x & 3;
    int nbase = g * NPG + part * NPB;
    int lane = threadIdx.x & 63;
    int wu = __builtin_amdgcn_readfirstlane(threadIdx.x >> 6);
    int c16 = lane & 15, g4 = lane >> 4, sh16 = g4 * 16;
    const unsigned* base = (const unsigned*)H1h;
    // ---- phase 1: gather pairs (waves cover nodes 0..27; node 28 by wave 2)
    for (int nl = wu * 2; nl + 1 < NPB; nl += 8) {
        int va = nbase + nl, vb = va + 1;
        int na = ncnt[va], nb = ncnt[vb];
        float a0, a1, a2, a3, b0, b1, b2v, b3;
        gather2n(base, ebuf, va, vb, na, nb, c16, g4, sh16,
                 a0, a1, a2, a3, b0, b1, b2v, b3);
        if (g4 == 0) {
            float4 m4; m4.x = a0; m4.y = a1; m4.z = a2; m4.w = a3;
            *(float4*)&Gs[nl][c16 * 4] = m4;
            m4.x = b0; m4.y = b1; m4.z = b2v; m4.w = b3;
            *(float4*)&Gs[nl + 1][c16 * 4] = m4;
        }
    }
    if (wu == 2) {   // leftover node 28
        int v = nbase + 28;
        int n = ncnt[v];
        float a0, a1, a2, a3, d0, d1, d2, d3;
        gather2n(base, ebuf, v, v, n, 0, c16, g4, sh16,
                 a0, a1, a2, a3, d0, d1, d2, d3);
        if (g4 == 0) {
            float4 m4; m4.x = a0; m4.y = a1; m4.z = a2; m4.w = a3;
            *(float4*)&Gs[28][c16 * 4] = m4;
        }
    }
    __syncthreads();
    // ---- phase 2: W2 matvec + activation + Wc dot
    float w2[F_HID];
    #pragma unroll
    for (int k = 0; k < F_HID; ++k) w2[k] = W2[k * F_HID + lane];
    float b2l = b2[lane];
    float s0 = 0.f, s1 = 0.f;
    for (int nl = wu; nl < NPB; nl += 4) {
        int v = nbase + nl;
        float acc = 0.f;
        #pragma unroll
        for (int k = 0; k < F_HID; k += 4) {
            float4 gk = *(const float4*)&Gs[nl][k];   // uniform addr: LDS broadcast
            acc += gk.x * w2[k] + gk.y * w2[k + 1] + gk.z * w2[k + 2] + gk.w * w2[k + 3];
        }
        float h = fmaxf(inorm[v] * acc + b2l, 0.f);
        float2 w = ((const float2*)Wc)[(part * NPB + nl) * F_HID + lane];
        s0 += h * w.x;
        s1 += h * w.y;
    }
    #pragma unroll
    for (int off = 32; off > 0; off >>= 1) {
        s0 += __shfl_down(s0, off);
        s1 += __shfl_down(s1, off);
    }
    if (lane == 0) { ls[wu * 2] = s0; ls[wu * 2 + 1] = s1; }
    __syncthreads();
    if (threadIdx.x < 2) {
        float t = 0.f;
        #pragma unroll
        for (int w = 0; w < 4; ++w) t += ls[w * 2 + threadIdx.x];
        if (part == 0) t += bc[threadIdx.x];
        atomicAdd(&out[g * 2 + threadIdx.x], t);
    }
}

extern "C" void kernel_launch(void* const* d_in, const int* in_sizes, int n_in,
                              void* d_out, int out_size, void* d_ws, size_t ws_size,
                              hipStream_t stream) {
    const float* feat = (const float*)d_in[0];
    const int*   src  = (const int*)d_in[1];
    const int*   dst  = (const int*)d_in[2];
    // d_in[3] = batch_size (fixed 512)
    const float* W1 = (const float*)d_in[4];
    const float* b1 = (const float*)d_in[5];
    const float* W2 = (const float*)d_in[6];
    const float* b2 = (const float*)d_in[7];
    const float* Wc = (const float*)d_in[8];
    const float* bc = (const float*)d_in[9];
    float* out = (float*)d_out;

    // ws layout (≈26 MB):
    // cnt2 u8[NSLD*N] (4.75MB) | cnt2s u8[NSLS*N] (4.75MB) | onorm f32[N+1] | inorm f32[N]
    // | ncnt i32[N] | (256B-aligned) ebuf u16[N*CCAP] | A1h bf16[(N+1)*64]
    // H1h (bf16[(N+1)*64] = 7.60MB) ALIASES cnt2+cnt2s (9.50MB; both dead after place).
    unsigned char* cnt2  = (unsigned char*)d_ws;
    unsigned char* cnt2s = cnt2 + (size_t)NSLD * N_NODES;
    float* onorm = (float*)(cnt2s + (size_t)NSLS * N_NODES);
    float* inorm = onorm + N_NODES + 1;
    int* ncnt    = (int*)(inorm + N_NODES);
    unsigned short* ebuf = (unsigned short*)(((unsigned long long)(ncnt + N_NODES) + 255ull) & ~255ull);
    unsigned short* A1h  = ebuf + (size_t)N_NODES * CCAP;
    unsigned short* H1h  = (unsigned short*)cnt2;   // alias (spans cnt2+cnt2s)

    hist_kernel<<<NSLD + NSLS, 1024, 0, stream>>>(src, dst, cnt2, cnt2s);
    scan_kernel<<<SCAN_BLK, 256, 0, stream>>>(cnt2, cnt2s, onorm, inorm, ncnt, A1h);
    gemm_place_kernel<<<NSLD + GEMM_BLK, 256, 0, stream>>>(src, dst, cnt2, ebuf,
                                                           feat, W1, onorm, A1h);
    gather1_kernel<<<N_NODES / 8, 256, 0, stream>>>(ncnt, ebuf, A1h, onorm, inorm, b1, H1h, out);
    readout_kernel<<<BATCH * GPB, 256, 0, stream>>>(ncnt, ebuf, H1h, inorm, b2, W2, Wc, bc, out);
}